// Round 17
// baseline (209.424 us; speedup 1.0000x reference)
//
#include <hip/hip_runtime.h>
#include <hip/hip_bf16.h>
#include <math.h>

#define Wd 128
#define Hd 128
#define HW 16384
#define CH 64
#define TT 8
#define NEGS 0.2f
#define PW 130                    // padded width/height
#define ROWB (PW * CH * 2)        // padded row bytes = 16640

typedef unsigned short u16;
typedef u16 u16x8 __attribute__((ext_vector_type(8)));
typedef u16 u16x4 __attribute__((ext_vector_type(4)));
typedef short bf16x8 __attribute__((ext_vector_type(8)));
typedef float f32x4 __attribute__((ext_vector_type(4)));

__device__ __forceinline__ u16 tobf(float v) {
  __hip_bfloat16 h = __float2bfloat16(v);
  return __builtin_bit_cast(u16, h);
}
__device__ __forceinline__ float bf2f(u16 u) {
  unsigned x = ((unsigned)u) << 16;
  return __builtin_bit_cast(float, x);
}
__device__ __forceinline__ void gload_lds16(const void* g, void* l) {
  __builtin_amdgcn_global_load_lds(
      (const __attribute__((address_space(1))) unsigned int*)g,
      (__attribute__((address_space(3))) unsigned int*)l, 16, 0, 0);
}

// Weight prep. 3x3 packs are now FRAGMENT-COALESCED for global A-reads:
// Wq[(s*64 + cout)*32 + (k&31)], s=k>>5 -> a wave's 16-cout A-load is one
// contiguous (lane-permuted) 1KB line. Also packs 1x1 (linear) and wk3
// ([16 couts zero-padded][576] linear, for convs2m's per-lane reads).
__global__ __launch_bounds__(256) void prep_k(
    const float* __restrict__ w1, const float* __restrict__ w2,
    const float* __restrict__ wk2, const float* __restrict__ wk1,
    const float* __restrict__ wk3,
    short* __restrict__ Wp1, short* __restrict__ Wp2,
    short* __restrict__ Wp4, short* __restrict__ Wk1b,
    short* __restrict__ Wp3)
{
  const int bx = blockIdx.x, y = blockIdx.y;
  if (bx < 144) {
    const float* w = (y == 0) ? w1 : (y == 1) ? w2 : wk2;
    short* out = (y == 0) ? Wp1 : (y == 1) ? Wp2 : Wp4;
    int i = bx * 256 + threadIdx.x;       // 36864
    int cout = i / 576, k = i - cout * 576;
    int off = k >> 6, cin = k & 63;
    int dy = off / 3, dx = off - dy * 3;
    int go = ((k >> 5) * 64 + cout) * 32 + (k & 31);
    out[go] = (short)tobf(w[((cout * 64 + cin) * 3 + dy) * 3 + dx]);
  } else if (y == 0 && bx < 160) {
    int i = (bx - 144) * 256 + threadIdx.x;   // 4096
    Wk1b[i] = (short)tobf(wk1[i]);
  } else if (y == 1) {
    int i = (bx - 144) * 256 + threadIdx.x;   // 9216 = 16 x 576
    if (i < 9216) {
      int cout = i / 576, k = i - cout * 576;
      int off = k >> 6, cin = k & 63;
      int dy = off / 3, dx = off - dy * 3;
      float v = (cout < 9) ? wk3[((cout * 64 + cin) * 3 + dy) * 3 + dx] : 0.f;
      Wp3[i] = (short)tobf(v);
    }
  }
}

// x (B,C,T,H,W) fp32 -> padded swizzled bf16 [f][130][130][64].
// Coalesced-read -> LDS transpose -> coalesced-write (R15).
__global__ __launch_bounds__(256) void xprep_k(const float* __restrict__ x,
                                               u16* __restrict__ outb)
{
  __shared__ __align__(16) u16 Sw[128 * 72];    // 18432 B
  const int f = blockIdx.x, b = f >> 3, t = f & 7;
  const int ph = blockIdx.y;                    // 0..129
  const int h = ph - 1;
  const bool rowok = (h >= 0 && h < Hd);
  const int tid = threadIdx.x;

  if (rowok) {
    const int cl = tid >> 5;        // channel within chunk (0..7)
    const int m  = tid & 31;
#pragma unroll 1
    for (int cc = 0; cc < 8; ++cc) {
      const int c = cc * 8 + cl;
      const float* src = x + (((size_t)(b * 64 + c) * 8 + t) * HW) + (size_t)h * Wd;
      const int oct = c >> 3, e = c & 7;
#pragma unroll
      for (int j = 0; j < 4; ++j) {
        const int w = m + 32 * j;               // coalesced per half-wave
        const float v = src[w];
        const int s = oct ^ ((w + 1) & 7);      // slot == output unit
        Sw[w * 72 + s * 8 + e] = tobf(v);
      }
    }
  }
  __syncthreads();

  const size_t obase = ((size_t)f * PW + ph) * PW * CH;
#pragma unroll 1
  for (int g = tid; g < 1040; g += 256) {       // 130 px x 8 units
    const int ppw = g >> 3, u = g & 7;
    u16x8 pk = (u16x8)0;
    if (rowok && ppw >= 1 && ppw <= 128)
      pk = *(const u16x8*)(Sw + (ppw - 1) * 72 + u * 8);
    *(u16x8*)(outb + obase + (size_t)ppw * CH + u * 8) = pk;
  }
}

// Zero the 1-pixel pad ring of two padded bf16 buffers (z selects buffer).
__global__ __launch_bounds__(256) void padzero_k(u16* __restrict__ a,
                                                 u16* __restrict__ b)
{
  u16* buf = (blockIdx.z == 0) ? a : b;
  const int f = blockIdx.y;
  u16* fb = buf + (size_t)f * PW * PW * CH;
  const int g = blockIdx.x * 256 + threadIdx.x;
  if (g >= 4128) return;
  size_t off;
  if (g < 1040)      off = (size_t)g * 8;
  else if (g < 2080) off = (size_t)129 * PW * CH + (size_t)(g - 1040) * 8;
  else if (g < 3104) { int r = (g - 2080) >> 3, u = (g - 2080) & 7;
                       off = ((size_t)(r + 1) * PW + 0) * CH + u * 8; }
  else               { int r = (g - 3104) >> 3, u = (g - 3104) & 7;
                       off = ((size_t)(r + 1) * PW + 129) * CH + u * 8; }
  *(u16x8*)(fb + off) = (u16x8)0;
}

// sm = r1 * shift(r1) on padded swizzled bf16 (ring rows give v=0 -> sm ring=0).
__global__ __launch_bounds__(256) void shmul_k(const u16* __restrict__ r1,
                                               u16* __restrict__ sm)
{
  const int f = blockIdx.x;
  const int ph = blockIdx.y;                    // 0..129
  const int us = threadIdx.x & 7;
  const int p0 = threadIdx.x >> 3;
#pragma unroll
  for (int i = 0; i < 5; ++i) {
    const int ppw = p0 + 32 * i;
    if (ppw < PW) {
      const int ub = us ^ (ppw & 7);            // physical channel octet
      const int g = ub >> 1;                    // 16-ch shift group
      const int dw = (g == 0) ? -4 : (g == 1) ? 4 : 0;
      const int dh = (g == 2) ? -4 : (g == 3) ? 4 : 0;
      const size_t idx = ((size_t)f * PW + ph) * PW * CH + (size_t)ppw * CH;
      u16x8 v = *(const u16x8*)(r1 + idx + us * 8);
      const int h2 = ph + dh, w2 = ppw + dw;
      const bool okp = (h2 >= 1 && h2 <= Hd && w2 >= 1 && w2 <= Wd);
      const int h2c = min(max(h2, 0), PW - 1);
      const int w2c = min(max(w2, 0), PW - 1);
      const int u2 = (dw != 0) ? (us ^ 4) : us;
      u16x8 pv = *(const u16x8*)(r1 + ((size_t)f * PW + h2c) * PW * CH +
                                 (size_t)w2c * CH + u2 * 8);
      u16x8 o;
#pragma unroll
      for (int j = 0; j < 8; ++j) {
        float pr = okp ? bf2f(v[j]) * bf2f(pv[j]) : 0.f;
        o[j] = tobf(pr);
      }
      *(u16x8*)(sm + idx + us * 8) = o;
    }
  }
}

// Persistent double-buffered 3x3 conv 64->64 via bf16 MFMA + lrelu.
// R16: 4-row stripes (6-row tiles, 52KB LDS -> 2 blocks/CU) + weights read
// from global via fragment-coalesced pack (1KB/wave A-load, L2-hot).
// 8 waves = 4 rows x 2 cout-halves; wave = 32 cout x 32 px, acc 2x2.
__global__ __launch_bounds__(512) void conv3x3_pers2_k(
    const u16* __restrict__ inp, const short* __restrict__ wgt,
    const float* __restrict__ bias, u16* __restrict__ outb)
{
  extern __shared__ __align__(16) char smem[];
  u16* Xb0 = (u16*)smem;                   // 26112 B (6 rows x 34 x 64)
  u16* Xb1 = (u16*)(smem + 26112);         // 26112 B

  const int bid = blockIdx.x;
  const int f = bid >> 5, hy = bid & 31;
  const int h0 = hy * 4;                   // out-row base; padded rows h0..h0+5
  const int tid = threadIdx.x;
  const int lane = tid & 63;
  const int wv = __builtin_amdgcn_readfirstlane(tid >> 6);
  const int r0 = wv >> 1;                  // 0..3 output row
  const int chh = wv & 1;                  // cout half
  const int l15 = lane & 15;
  const int oct = lane >> 4;

  f32x4 b4[2];
#pragma unroll
  for (int cg = 0; cg < 2; ++cg)
#pragma unroll
    for (int rr = 0; rr < 4; ++rr)
      b4[cg][rr] = bias[chh * 32 + cg * 16 + oct * 4 + rr];

  const size_t fbase = (size_t)f * PW * PW * CH;
  const char* fbp = (const char*)(inp + fbase);

  {
    const char* tb = fbp + (size_t)h0 * ROWB;
    char* ld = (char*)Xb0;
#pragma unroll 1
    for (int i = wv; i < 26; i += 8) {
      const int ob = i * 1024 + lane * 16;
      if (ob < 26112) {
        const int row = ob / 4352;
        const int rem = ob - row * 4352;
        gload_lds16(tb + (size_t)row * ROWB + rem, ld + ob);
      }
    }
  }

#pragma unroll 1
  for (int it = 0; it < 4; ++it) {
    __syncthreads();
    u16* Xc = (it & 1) ? Xb1 : Xb0;
    u16* Xn = (it & 1) ? Xb0 : Xb1;
    if (it < 3) {
      const char* tb = fbp + (size_t)h0 * ROWB + (size_t)(it + 1) * 32 * CH * 2;
      char* ld = (char*)Xn;
#pragma unroll 1
      for (int i = wv; i < 26; i += 8) {
        const int ob = i * 1024 + lane * 16;
        if (ob < 26112) {
          const int row = ob / 4352;
          const int rem = ob - row * 4352;
          gload_lds16(tb + (size_t)row * ROWB + rem, ld + ob);
        }
      }
    }
    const int w0 = it * 32;

    f32x4 acc[2][2];
#pragma unroll
    for (int i = 0; i < 2; ++i)
#pragma unroll
      for (int j = 0; j < 2; ++j) acc[i][j] = (f32x4)0.f;

#pragma unroll 1
    for (int s = 0; s < 18; ++s) {
      const int o = s >> 1;
      const int dy = o / 3, dx = o - dy * 3;
      const int half = s & 1;
      bf16x8 a[2];
#pragma unroll
      for (int cg = 0; cg < 2; ++cg)
        a[cg] = *(const bf16x8*)(wgt + (s * 64 + chh * 32 + cg * 16 + l15) * 32 + oct * 8);
#pragma unroll
      for (int pt = 0; pt < 2; ++pt) {
        const int r = r0 + dy;
        const int cc = pt * 16 + dx + l15;
        const int p = r * 34 + cc;
        const int co = ((half * 4 + oct) ^ (cc & 7)) << 3;
        bf16x8 b = *(const bf16x8*)((const short*)Xc + p * 64 + co);
#pragma unroll
        for (int cg = 0; cg < 2; ++cg)
          acc[cg][pt] = __builtin_amdgcn_mfma_f32_16x16x32_bf16(a[cg], b, acc[cg][pt], 0, 0, 0);
      }
    }

#pragma unroll
    for (int cg = 0; cg < 2; ++cg)
#pragma unroll
      for (int pt = 0; pt < 2; ++pt) {
        const int pph = h0 + r0 + 1;
        const int ppw = w0 + pt * 16 + l15 + 1;
        const int unit = (chh * 4 + cg * 2 + (oct >> 1)) ^ (ppw & 7);
        u16x4 pk;
#pragma unroll
        for (int rr = 0; rr < 4; ++rr) {
          float t2 = acc[cg][pt][rr] + b4[cg][rr];
          t2 = (t2 >= 0.f) ? t2 : NEGS * t2;
          pk[rr] = tobf(t2);
        }
        *(u16x4*)(outb + fbase + ((size_t)pph * PW + ppw) * CH +
                  unit * 8 + (oct & 1) * 4) = pk;
      }
  }
}

// Persistent x5 conv (R16 4-row-stripe variant): x5 = x + conv3x3(sm,w2) + b2
// (bf16 padded) and k = wk1 @ x5 + bk1 (bf16 padded). Ys 1x1 round-trip
// reuses the consumed tile buffer (128px x 64ch = 16KB <= 26KB).
__global__ __launch_bounds__(512) void convx5_pers2_k(
    const u16* __restrict__ inp, const short* __restrict__ wgt,
    const float* __restrict__ bias, const u16* __restrict__ xp,
    const short* __restrict__ w1b, const float* __restrict__ b1x1,
    u16* __restrict__ outx, u16* __restrict__ outk)
{
  extern __shared__ __align__(16) char smem[];
  u16* Xb0 = (u16*)smem;                   // 26112 B
  u16* Xb1 = (u16*)(smem + 26112);         // 26112 B

  const int bid = blockIdx.x;
  const int f = bid >> 5, hy = bid & 31;
  const int h0 = hy * 4;
  const int tid = threadIdx.x;
  const int lane = tid & 63;
  const int wv = __builtin_amdgcn_readfirstlane(tid >> 6);
  const int r0 = wv >> 1;
  const int chh = wv & 1;
  const int l15 = lane & 15;
  const int oct = lane >> 4;

  f32x4 b4[2], bb1[2];
#pragma unroll
  for (int cg = 0; cg < 2; ++cg)
#pragma unroll
    for (int rr = 0; rr < 4; ++rr) {
      b4[cg][rr]  = bias[chh * 32 + cg * 16 + oct * 4 + rr];
      bb1[cg][rr] = b1x1[chh * 32 + cg * 16 + oct * 4 + rr];
    }
  bf16x8 a1_0[2], a1_1[2];      // 1x1 weight frags (s=0,1) for this half
#pragma unroll
  for (int cg = 0; cg < 2; ++cg) {
    const int kout = chh * 32 + cg * 16 + l15;
    a1_0[cg] = *(const bf16x8*)(w1b + kout * 64 + 0 * 32 + oct * 8);
    a1_1[cg] = *(const bf16x8*)(w1b + kout * 64 + 1 * 32 + oct * 8);
  }

  const size_t fbase = (size_t)f * PW * PW * CH;
  const char* fbp = (const char*)(inp + fbase);

  {
    const char* tb = fbp + (size_t)h0 * ROWB;
    char* ld = (char*)Xb0;
#pragma unroll 1
    for (int i = wv; i < 26; i += 8) {
      const int ob = i * 1024 + lane * 16;
      if (ob < 26112) {
        const int row = ob / 4352;
        const int rem = ob - row * 4352;
        gload_lds16(tb + (size_t)row * ROWB + rem, ld + ob);
      }
    }
  }

#pragma unroll 1
  for (int it = 0; it < 4; ++it) {
    __syncthreads();                             // stage(it) ready
    u16* Xc = (it & 1) ? Xb1 : Xb0;
    u16* Xn = (it & 1) ? Xb0 : Xb1;
    if (it < 3) {
      const char* tb = fbp + (size_t)h0 * ROWB + (size_t)(it + 1) * 32 * CH * 2;
      char* ld = (char*)Xn;
#pragma unroll 1
      for (int i = wv; i < 26; i += 8) {
        const int ob = i * 1024 + lane * 16;
        if (ob < 26112) {
          const int row = ob / 4352;
          const int rem = ob - row * 4352;
          gload_lds16(tb + (size_t)row * ROWB + rem, ld + ob);
        }
      }
    }
    const int w0 = it * 32;
    const int pph = h0 + r0 + 1;

    // issue xres loads early (T14)
    u16x4 xrv[2][2];
    size_t gaddr[2][2];
#pragma unroll
    for (int cg = 0; cg < 2; ++cg)
#pragma unroll
      for (int pt = 0; pt < 2; ++pt) {
        const int ppw = w0 + pt * 16 + l15 + 1;
        const int unitg = (chh * 4 + cg * 2 + (oct >> 1)) ^ (ppw & 7);
        gaddr[cg][pt] = fbase + ((size_t)pph * PW + ppw) * CH + unitg * 8 + (oct & 1) * 4;
        xrv[cg][pt] = *(const u16x4*)(xp + gaddr[cg][pt]);
      }

    f32x4 acc[2][2];
#pragma unroll
    for (int i = 0; i < 2; ++i)
#pragma unroll
      for (int j = 0; j < 2; ++j) acc[i][j] = (f32x4)0.f;

#pragma unroll 1
    for (int s = 0; s < 18; ++s) {
      const int o = s >> 1;
      const int dy = o / 3, dx = o - dy * 3;
      const int half = s & 1;
      bf16x8 a[2];
#pragma unroll
      for (int cg = 0; cg < 2; ++cg)
        a[cg] = *(const bf16x8*)(wgt + (s * 64 + chh * 32 + cg * 16 + l15) * 32 + oct * 8);
#pragma unroll
      for (int pt = 0; pt < 2; ++pt) {
        const int r = r0 + dy;
        const int cc = pt * 16 + dx + l15;
        const int p = r * 34 + cc;
        const int co = ((half * 4 + oct) ^ (cc & 7)) << 3;
        bf16x8 b = *(const bf16x8*)((const short*)Xc + p * 64 + co);
#pragma unroll
        for (int cg = 0; cg < 2; ++cg)
          acc[cg][pt] = __builtin_amdgcn_mfma_f32_16x16x32_bf16(a[cg], b, acc[cg][pt], 0, 0, 0);
      }
    }

    __syncthreads();            // all Xc reads done -> reuse as Ys
    u16* Ys = Xc;               // [128 px][64 ch], XOR swizzle on (p2&7)

    // epilogue 1: x5 = acc + b2 + x(bf16) -> global store + Ys stash
#pragma unroll
    for (int cg = 0; cg < 2; ++cg)
#pragma unroll
      for (int pt = 0; pt < 2; ++pt) {
        const int lc = pt * 16 + l15;
        const int p2 = r0 * 32 + lc;
        u16x4 pk;
#pragma unroll
        for (int rr = 0; rr < 4; ++rr) {
          float v = acc[cg][pt][rr] + b4[cg][rr] + bf2f(xrv[cg][pt][rr]);
          pk[rr] = tobf(v);
        }
        *(u16x4*)(outx + gaddr[cg][pt]) = pk;
        const int unit2 = (chh * 4 + cg * 2 + (oct >> 1)) ^ (p2 & 7);
        *(u16x4*)(Ys + p2 * 64 + unit2 * 8 + (oct & 1) * 4) = pk;
      }
    __syncthreads();            // Ys visible

    // phase 2: k = wk1 @ x5 + bk1 (2 MFMA k-steps, reg weights)
    f32x4 acc2[2][2];
#pragma unroll
    for (int i = 0; i < 2; ++i)
#pragma unroll
      for (int j = 0; j < 2; ++j) acc2[i][j] = (f32x4)0.f;

#pragma unroll
    for (int pt = 0; pt < 2; ++pt) {
      const int p2 = r0 * 32 + pt * 16 + l15;
      const int co0 = ((0 * 4 + oct) ^ (p2 & 7)) << 3;
      const int co1 = ((1 * 4 + oct) ^ (p2 & 7)) << 3;
      bf16x8 bv0 = *(const bf16x8*)((const short*)Ys + p2 * 64 + co0);
      bf16x8 bv1 = *(const bf16x8*)((const short*)Ys + p2 * 64 + co1);
#pragma unroll
      for (int cg = 0; cg < 2; ++cg) {
        acc2[cg][pt] = __builtin_amdgcn_mfma_f32_16x16x32_bf16(a1_0[cg], bv0, acc2[cg][pt], 0, 0, 0);
        acc2[cg][pt] = __builtin_amdgcn_mfma_f32_16x16x32_bf16(a1_1[cg], bv1, acc2[cg][pt], 0, 0, 0);
      }
    }

    // epilogue 2: k + bk1 -> bf16 padded
#pragma unroll
    for (int cg = 0; cg < 2; ++cg)
#pragma unroll
      for (int pt = 0; pt < 2; ++pt) {
        u16x4 pk;
#pragma unroll
        for (int rr = 0; rr < 4; ++rr)
          pk[rr] = tobf(acc2[cg][pt][rr] + bb1[cg][rr]);
        *(u16x4*)(outk + gaddr[cg][pt]) = pk;
      }
  }
}

// stride-2 3x3 conv 64->9 via bf16 MFMA. Block = (hy, f): 4 out rows x 64
// cols; stage 9 contiguous padded rows whole; A = wk3 [16][576] bf16.
__global__ __launch_bounds__(512) void convs2m_k(
    const u16* __restrict__ inb, const short* __restrict__ w3b,
    const float* __restrict__ bk3, float* __restrict__ sc)
{
  extern __shared__ __align__(16) char smem[];
  u16* St = (u16*)smem;                 // 9 rows x 130 px x 64 ch = 149760 B
  const int hy = blockIdx.x;            // 0..15 -> out rows 4hy..4hy+3
  const int f  = blockIdx.y;            // 0..15
  const int tid = threadIdx.x;
  const int lane = tid & 63;
  const int wv = __builtin_amdgcn_readfirstlane(tid >> 6);  // 0..7
  const int l15 = lane & 15;
  const int oct = lane >> 4;

  const char* fbp = (const char*)(inb + (size_t)f * PW * PW * CH) +
                    (size_t)(8 * hy) * ROWB;
  char* ld = (char*)St;
#pragma unroll 1
  for (int g = tid; g < 9360; g += 512)         // 9360 x 16B granules
    gload_lds16(fbp + g * 16, ld + g * 16);
  __syncthreads();

  f32x4 acc[2];
  acc[0] = (f32x4)0.f;
  acc[1] = (f32x4)0.f;

#pragma unroll 2
  for (int s = 0; s < 18; ++s) {
    const int o = s >> 1;                       // tap 0..8
    const int dy = o / 3, dx = o - dy * 3;
    const int half = s & 1;                     // cin half
    bf16x8 a = *(const bf16x8*)(w3b + l15 * 576 + s * 32 + oct * 8);
#pragma unroll
    for (int pg = 0; pg < 2; ++pg) {
      const int g = wv * 2 + pg;                // px-group 0..15
      const int ho_l = g >> 2, wg = g & 3;
      const int wo = wg * 16 + l15;
      const int irow = 2 * ho_l + dy;           // 0..8
      const int ipx = 2 * wo + dx;              // 0..128 (== global ppw)
      const int slot = (half * 4 + oct) ^ (ipx & 7);
      bf16x8 b = *(const bf16x8*)((const short*)St + (irow * PW + ipx) * 64 + slot * 8);
      acc[pg] = __builtin_amdgcn_mfma_f32_16x16x32_bf16(a, b, acc[pg], 0, 0, 0);
    }
  }

#pragma unroll
  for (int pg = 0; pg < 2; ++pg) {
    const int g = wv * 2 + pg;
    const int ho = hy * 4 + (g >> 2);
    const int wo = (g & 3) * 16 + l15;
#pragma unroll
    for (int rr = 0; rr < 4; ++rr) {
      const int kk = oct * 4 + rr;
      if (kk < 9)
        sc[((size_t)f * 9 + kk) * 4096 + ho * 64 + wo] = acc[pg][rr] + bk3[kk];
    }
  }
}

// Fused softmax + weighted patch reduce from padded swizzled bf16 x5.
__global__ __launch_bounds__(256) void gather2_k(
    const u16* __restrict__ x5p, const float* __restrict__ sc,
    float* __restrict__ out)
{
  const int hx = blockIdx.x;       // wo half (0..1)
  const int ho = blockIdx.y;       // 0..63
  const int b  = blockIdx.z;       // 0..1
  const int wo0 = hx * 32;
  __shared__ float wl[32 * 73];
  for (int e = threadIdx.x; e < 32 * 72; e += 256) {
    const int wo = e & 31, k = e >> 5;
    const int t = k / 9, kk = k - t * 9;
    wl[wo * 73 + k] = sc[((size_t)((b * 8 + t) * 9 + kk)) * 4096 + ho * 64 + wo0 + wo];
  }
  __syncthreads();
  if (threadIdx.x < 32) {
    float* row = &wl[threadIdx.x * 73];
    float mx = -1e30f;
#pragma unroll
    for (int i = 0; i < 72; ++i) mx = fmaxf(mx, row[i]);
    float sum = 0.f;
#pragma unroll
    for (int i = 0; i < 72; ++i) { float e2 = __expf(row[i] - mx); row[i] = e2; sum += e2; }
    const float inv = 1.f / sum;
#pragma unroll
    for (int i = 0; i < 72; ++i) row[i] *= inv;
  }
  __syncthreads();
  const int lane = threadIdx.x & 63;
  const int wv = threadIdx.x >> 6;
  const int u = lane & 7;                 // channel octet
  const int wol = (lane >> 3) + wv * 8;   // 0..31
  const int wo = wo0 + wol;
  float acc[8];
#pragma unroll
  for (int j = 0; j < 8; ++j) acc[j] = 0.f;
#pragma unroll 1
  for (int t = 0; t < 8; ++t) {
    const int f = b * 8 + t;
    const size_t fb = (size_t)f * PW * PW * CH;
    const float* wrow = &wl[wol * 73 + t * 9];
#pragma unroll
    for (int di = 0; di < 3; ++di) {
      const int pph = min(max(2 * ho + di, 1), 128);
#pragma unroll
      for (int dj = 0; dj < 3; ++dj) {
        const int ppw = min(max(2 * wo + dj, 1), 128);
        const int unit = u ^ (ppw & 7);
        u16x8 pk = *(const u16x8*)(x5p + fb + ((size_t)pph * PW + ppw) * CH + unit * 8);
        const float wq = wrow[di * 3 + dj];
#pragma unroll
        for (int j = 0; j < 8; ++j)
          acc[j] = fmaf(bf2f(pk[j]), wq, acc[j]);
      }
    }
  }
  const int obase = ((b * 64 + u * 8) * 64 + ho) * 64 + wo;
#pragma unroll
  for (int j = 0; j < 8; ++j)
    out[obase + j * 4096] = acc[j];
}

extern "C" void kernel_launch(void* const* d_in, const int* in_sizes, int n_in,
                              void* d_out, int out_size, void* d_ws, size_t ws_size,
                              hipStream_t stream)
{
  const float* x   = (const float*)d_in[0];
  const float* w1  = (const float*)d_in[1];
  const float* b1  = (const float*)d_in[2];
  const float* w2  = (const float*)d_in[3];
  const float* b2  = (const float*)d_in[4];
  const float* wk1 = (const float*)d_in[5];
  const float* bk1 = (const float*)d_in[6];
  const float* wk2 = (const float*)d_in[7];
  const float* bk2 = (const float*)d_in[8];
  const float* wk3 = (const float*)d_in[9];
  const float* bk3 = (const float*)d_in[10];
  float* outp = (float*)d_out;

  const size_t PADB = (size_t)16 * PW * PW * CH * 2;   // 34,611,200 B
  char* ws = (char*)d_ws;
  u16*  P1      = (u16*)ws;                            // x bf16, then kf2
  u16*  P2      = (u16*)(ws + PADB);                   // res1
  u16*  P3      = (u16*)(ws + 2 * PADB);               // k
  u16*  P4      = (u16*)(ws + 3 * PADB);               // x5 bf16
  u16*  P5      = (u16*)(ws + 4 * PADB);               // sm
  float* scores = (float*)(ws + 5 * PADB);             // 2.25 MB
  short* Wp1    = (short*)(ws + 5 * PADB + 2359296);
  short* Wp2    = Wp1 + 36864;
  short* Wp4    = Wp2 + 36864;
  short* Wk1b   = Wp4 + 36864;                         // 4096 bf16
  short* Wp3    = Wk1b + 4096;                         // 9216 bf16 (wk3, padded)
  (void)ws_size; (void)in_sizes; (void)n_in; (void)out_size;

  hipFuncSetAttribute((const void*)conv3x3_pers2_k,
                      hipFuncAttributeMaxDynamicSharedMemorySize, 52224);
  hipFuncSetAttribute((const void*)convx5_pers2_k,
                      hipFuncAttributeMaxDynamicSharedMemorySize, 52224);
  hipFuncSetAttribute((const void*)convs2m_k,
                      hipFuncAttributeMaxDynamicSharedMemorySize, 149760);

  // weight packs (merged)
  prep_k<<<dim3(180, 3), 256, 0, stream>>>(w1, w2, wk2, wk1, wk3,
                                           Wp1, Wp2, Wp4, Wk1b, Wp3);
  // x -> padded swizzled bf16 (ring = 0), coalesced transpose version
  xprep_k<<<dim3(16, PW), 256, 0, stream>>>(x, P1);
  // zero pad rings for res1, k
  padzero_k<<<dim3(17, 16, 2), 256, 0, stream>>>(P2, P3);

  // 1: res1 = lrelu(conv(x, w1) + b1)                    -> P2
  conv3x3_pers2_k<<<dim3(512), 512, 52224, stream>>>(P1, Wp1, b1, P2);
  // 2: sm = res1 * shift(res1)                           -> P5 (ring 0)
  shmul_k<<<dim3(16, PW), 256, 0, stream>>>(P2, P5);
  // 3: x5 = x + conv(sm, w2) + b2 (bf16) -> P4; k = wk1@x5 + bk1 -> P3
  convx5_pers2_k<<<dim3(512), 512, 52224, stream>>>(P5, Wp2, b2, P1, Wk1b, bk1, P4, P3);
  // 4: kf2 = lrelu(conv(k, wk2) + bk2)                   -> P1 (ring 0 from xprep)
  conv3x3_pers2_k<<<dim3(512), 512, 52224, stream>>>(P3, Wp4, bk2, P1);
  // 5: scores = conv_s2(kf2, wk3) + bk3 via MFMA         -> scores
  convs2m_k<<<dim3(16, 16), 512, 149760, stream>>>(P1, Wp3, bk3, scores);
  // 6: fused softmax + weighted gather (bf16 x5)
  gather2_k<<<dim3(2, 64, 2), 256, 0, stream>>>(P4, scores, outp);
}

// Round 18
// 155.951 us; speedup vs baseline: 1.3429x; 1.3429x over previous
//
#include <hip/hip_runtime.h>
#include <hip/hip_bf16.h>
#include <math.h>

#define Wd 128
#define Hd 128
#define HW 16384
#define CH 64
#define TT 8
#define NEGS 0.2f
#define PW 130                    // padded width/height
#define ROWB (PW * CH * 2)        // padded row bytes = 16640

typedef unsigned short u16;
typedef u16 u16x8 __attribute__((ext_vector_type(8)));
typedef u16 u16x4 __attribute__((ext_vector_type(4)));
typedef short bf16x8 __attribute__((ext_vector_type(8)));
typedef float f32x4 __attribute__((ext_vector_type(4)));

__device__ __forceinline__ u16 tobf(float v) {
  __hip_bfloat16 h = __float2bfloat16(v);
  return __builtin_bit_cast(u16, h);
}
__device__ __forceinline__ float bf2f(u16 u) {
  unsigned x = ((unsigned)u) << 16;
  return __builtin_bit_cast(float, x);
}
__device__ __forceinline__ void gload_lds16(const void* g, void* l) {
  __builtin_amdgcn_global_load_lds(
      (const __attribute__((address_space(1))) unsigned int*)g,
      (__attribute__((address_space(3))) unsigned int*)l, 16, 0, 0);
}

// Merged weight prep: 3x packw (granule-XOR-swizzled bf16 [cout][k] for the
// LDS-resident A-reads — R16's global-read pack regressed, reverted),
// 1x1 pack, and wk3 pack ([16 couts zero-padded][576] linear bf16).
__global__ __launch_bounds__(256) void prep_k(
    const float* __restrict__ w1, const float* __restrict__ w2,
    const float* __restrict__ wk2, const float* __restrict__ wk1,
    const float* __restrict__ wk3,
    short* __restrict__ Wp1, short* __restrict__ Wp2,
    short* __restrict__ Wp4, short* __restrict__ Wk1b,
    short* __restrict__ Wp3)
{
  const int bx = blockIdx.x, y = blockIdx.y;
  if (bx < 144) {
    const float* w = (y == 0) ? w1 : (y == 1) ? w2 : wk2;
    short* out = (y == 0) ? Wp1 : (y == 1) ? Wp2 : Wp4;
    int i = bx * 256 + threadIdx.x;       // 36864
    int cout = i / 576, k = i - cout * 576;
    int off = k >> 6, cin = k & 63;
    int dy = off / 3, dx = off - dy * 3;
    int gi = cout * 72 + (k >> 3);
    int go = ((gi ^ (cout & 7)) << 3) + (k & 7);
    out[go] = (short)tobf(w[((cout * 64 + cin) * 3 + dy) * 3 + dx]);
  } else if (y == 0 && bx < 160) {
    int i = (bx - 144) * 256 + threadIdx.x;   // 4096
    Wk1b[i] = (short)tobf(wk1[i]);
  } else if (y == 1) {
    int i = (bx - 144) * 256 + threadIdx.x;   // 9216 = 16 x 576
    if (i < 9216) {
      int cout = i / 576, k = i - cout * 576;
      int off = k >> 6, cin = k & 63;
      int dy = off / 3, dx = off - dy * 3;
      float v = (cout < 9) ? wk3[((cout * 64 + cin) * 3 + dy) * 3 + dx] : 0.f;
      Wp3[i] = (short)tobf(v);
    }
  }
}

// x (B,C,T,H,W) fp32 -> padded swizzled bf16 [f][130][130][64].
// Coalesced-read -> LDS transpose -> coalesced-write (R15).
__global__ __launch_bounds__(256) void xprep_k(const float* __restrict__ x,
                                               u16* __restrict__ outb)
{
  __shared__ __align__(16) u16 Sw[128 * 72];    // 18432 B
  const int f = blockIdx.x, b = f >> 3, t = f & 7;
  const int ph = blockIdx.y;                    // 0..129
  const int h = ph - 1;
  const bool rowok = (h >= 0 && h < Hd);
  const int tid = threadIdx.x;

  if (rowok) {
    const int cl = tid >> 5;        // channel within chunk (0..7)
    const int m  = tid & 31;
#pragma unroll 1
    for (int cc = 0; cc < 8; ++cc) {
      const int c = cc * 8 + cl;
      const float* src = x + (((size_t)(b * 64 + c) * 8 + t) * HW) + (size_t)h * Wd;
      const int oct = c >> 3, e = c & 7;
#pragma unroll
      for (int j = 0; j < 4; ++j) {
        const int w = m + 32 * j;               // coalesced per half-wave
        const float v = src[w];
        const int s = oct ^ ((w + 1) & 7);      // slot == output unit
        Sw[w * 72 + s * 8 + e] = tobf(v);
      }
    }
  }
  __syncthreads();

  const size_t obase = ((size_t)f * PW + ph) * PW * CH;
#pragma unroll 1
  for (int g = tid; g < 1040; g += 256) {       // 130 px x 8 units
    const int ppw = g >> 3, u = g & 7;
    u16x8 pk = (u16x8)0;
    if (rowok && ppw >= 1 && ppw <= 128)
      pk = *(const u16x8*)(Sw + (ppw - 1) * 72 + u * 8);
    *(u16x8*)(outb + obase + (size_t)ppw * CH + u * 8) = pk;
  }
}

// Zero the 1-pixel pad ring of two padded bf16 buffers (z selects buffer).
__global__ __launch_bounds__(256) void padzero_k(u16* __restrict__ a,
                                                 u16* __restrict__ b)
{
  u16* buf = (blockIdx.z == 0) ? a : b;
  const int f = blockIdx.y;
  u16* fb = buf + (size_t)f * PW * PW * CH;
  const int g = blockIdx.x * 256 + threadIdx.x;
  if (g >= 4128) return;
  size_t off;
  if (g < 1040)      off = (size_t)g * 8;
  else if (g < 2080) off = (size_t)129 * PW * CH + (size_t)(g - 1040) * 8;
  else if (g < 3104) { int r = (g - 2080) >> 3, u = (g - 2080) & 7;
                       off = ((size_t)(r + 1) * PW + 0) * CH + u * 8; }
  else               { int r = (g - 3104) >> 3, u = (g - 3104) & 7;
                       off = ((size_t)(r + 1) * PW + 129) * CH + u * 8; }
  *(u16x8*)(fb + off) = (u16x8)0;
}

// sm = r1 * shift(r1) on padded swizzled bf16 (ring rows give v=0 -> sm ring=0).
__global__ __launch_bounds__(256) void shmul_k(const u16* __restrict__ r1,
                                               u16* __restrict__ sm)
{
  const int f = blockIdx.x;
  const int ph = blockIdx.y;                    // 0..129
  const int us = threadIdx.x & 7;
  const int p0 = threadIdx.x >> 3;
#pragma unroll
  for (int i = 0; i < 5; ++i) {
    const int ppw = p0 + 32 * i;
    if (ppw < PW) {
      const int ub = us ^ (ppw & 7);            // physical channel octet
      const int g = ub >> 1;                    // 16-ch shift group
      const int dw = (g == 0) ? -4 : (g == 1) ? 4 : 0;
      const int dh = (g == 2) ? -4 : (g == 3) ? 4 : 0;
      const size_t idx = ((size_t)f * PW + ph) * PW * CH + (size_t)ppw * CH;
      u16x8 v = *(const u16x8*)(r1 + idx + us * 8);
      const int h2 = ph + dh, w2 = ppw + dw;
      const bool okp = (h2 >= 1 && h2 <= Hd && w2 >= 1 && w2 <= Wd);
      const int h2c = min(max(h2, 0), PW - 1);
      const int w2c = min(max(w2, 0), PW - 1);
      const int u2 = (dw != 0) ? (us ^ 4) : us;
      u16x8 pv = *(const u16x8*)(r1 + ((size_t)f * PW + h2c) * PW * CH +
                                 (size_t)w2c * CH + u2 * 8);
      u16x8 o;
#pragma unroll
      for (int j = 0; j < 8; ++j) {
        float pr = okp ? bf2f(v[j]) * bf2f(pv[j]) : 0.f;
        o[j] = tobf(pr);
      }
      *(u16x8*)(sm + idx + us * 8) = o;
    }
  }
}

// Persistent double-buffered 3x3 conv 64->64 via bf16 MFMA + lrelu.
// R15-proven form: weights in LDS (staged once), 8-row stripes, pure-LDS
// K-loop (R16's global A-reads in the K-loop regressed 40->56us; reverted).
__global__ __launch_bounds__(512) void conv3x3_pers_k(
    const u16* __restrict__ inp, const short* __restrict__ wsw,
    const float* __restrict__ bias, u16* __restrict__ outb)
{
  extern __shared__ __align__(16) char smem[];
  short* Ws = (short*)smem;                          // 73728 B
  u16* Xb0 = (u16*)(smem + 73728);                   // 44032 B
  u16* Xb1 = (u16*)(smem + 73728 + 44032);           // 44032 B

  const int bid = blockIdx.x;
  const int f = bid >> 4, hy = bid & 15;
  const int h0 = hy * 8;
  const int tid = threadIdx.x;
  const int lane = tid & 63;
  const int wv = __builtin_amdgcn_readfirstlane(tid >> 6);  // 0..7
  const int l15 = lane & 15;
  const int oct = lane >> 4;

  f32x4 b4[4];
#pragma unroll
  for (int cg = 0; cg < 4; ++cg)
#pragma unroll
    for (int rr = 0; rr < 4; ++rr)
      b4[cg][rr] = bias[cg * 16 + oct * 4 + rr];

  {
    const char* gs = (const char*)wsw;
    char* ld = (char*)Ws;
#pragma unroll 1
    for (int i = wv; i < 72; i += 8)
      gload_lds16(gs + i * 1024 + lane * 16, ld + i * 1024);
  }

  const char* fbp = (const char*)(inp + (size_t)f * PW * PW * CH);

  {
    const char* tb = fbp + (size_t)h0 * ROWB;
    char* ld = (char*)Xb0;
#pragma unroll 1
    for (int i = wv; i < 43; i += 8) {
      const int ob = i * 1024 + lane * 16;
      const int row = ob / 4352;
      const int rem = ob - row * 4352;
      gload_lds16(tb + (size_t)row * ROWB + rem, ld + i * 1024);
    }
  }

#pragma unroll 1
  for (int it = 0; it < 4; ++it) {
    __syncthreads();
    u16* Xc = (it & 1) ? Xb1 : Xb0;
    u16* Xn = (it & 1) ? Xb0 : Xb1;
    if (it < 3) {
      const char* tb = fbp + (size_t)h0 * ROWB + (size_t)(it + 1) * 32 * CH * 2;
      char* ld = (char*)Xn;
#pragma unroll 1
      for (int i = wv; i < 43; i += 8) {
        const int ob = i * 1024 + lane * 16;
        const int row = ob / 4352;
        const int rem = ob - row * 4352;
        gload_lds16(tb + (size_t)row * ROWB + rem, ld + i * 1024);
      }
    }
    const int w0 = it * 32;

    f32x4 acc[4][2];
#pragma unroll
    for (int i = 0; i < 4; ++i)
#pragma unroll
      for (int j = 0; j < 2; ++j) acc[i][j] = (f32x4)0.f;

#pragma unroll 1
    for (int s = 0; s < 18; ++s) {
      const int o = s >> 1;
      const int dy = o / 3, dx = o - dy * 3;
      const int half = s & 1;
      bf16x8 a[4];
#pragma unroll
      for (int cg = 0; cg < 4; ++cg) {
        const int gi = (cg * 16 + l15) * 72 + s * 4 + oct;
        a[cg] = *(const bf16x8*)(Ws + ((gi ^ (l15 & 7)) << 3));
      }
#pragma unroll
      for (int pt = 0; pt < 2; ++pt) {
        const int r = wv + dy;
        const int cc = pt * 16 + dx + l15;
        const int p = r * 34 + cc;
        const int co = ((half * 4 + oct) ^ (cc & 7)) << 3;
        bf16x8 b = *(const bf16x8*)((const short*)Xc + p * 64 + co);
#pragma unroll
        for (int cg = 0; cg < 4; ++cg)
          acc[cg][pt] = __builtin_amdgcn_mfma_f32_16x16x32_bf16(a[cg], b, acc[cg][pt], 0, 0, 0);
      }
    }

#pragma unroll
    for (int cg = 0; cg < 4; ++cg)
#pragma unroll
      for (int pt = 0; pt < 2; ++pt) {
        const int py = h0 + wv;
        const int px = w0 + pt * 16 + l15;
        const int pph = py + 1, ppw = px + 1;
        const int unit = (cg * 2 + (oct >> 1)) ^ (ppw & 7);
        u16x4 pk;
#pragma unroll
        for (int rr = 0; rr < 4; ++rr) {
          float t2 = acc[cg][pt][rr] + b4[cg][rr];
          t2 = (t2 >= 0.f) ? t2 : NEGS * t2;
          pk[rr] = tobf(t2);
        }
        *(u16x4*)(outb + ((size_t)f * PW + pph) * PW * CH + (size_t)ppw * CH +
                  unit * 8 + (oct & 1) * 4) = pk;
      }
  }
}

// Persistent x5 conv (R15-proven form): x5 = x + conv3x3(sm, w2) + b2 (bf16
// padded out) and k = wk1 @ x5 + bk1 (bf16 padded out).
__global__ __launch_bounds__(512) void convx5_pers_k(
    const u16* __restrict__ inp, const short* __restrict__ wsw,
    const float* __restrict__ bias, const u16* __restrict__ xp,
    const short* __restrict__ w1b, const float* __restrict__ b1x1,
    u16* __restrict__ outx, u16* __restrict__ outk)
{
  extern __shared__ __align__(16) char smem[];
  short* Ws = (short*)smem;                          // 73728 B
  u16* Xb0 = (u16*)(smem + 73728);                   // 44032 B
  u16* Xb1 = (u16*)(smem + 73728 + 44032);           // 44032 B

  const int bid = blockIdx.x;
  const int f = bid >> 4, hy = bid & 15;
  const int h0 = hy * 8;
  const int tid = threadIdx.x;
  const int lane = tid & 63;
  const int wv = __builtin_amdgcn_readfirstlane(tid >> 6);  // 0..7 = row
  const int l15 = lane & 15;
  const int oct = lane >> 4;

  f32x4 b4[4], bb1[4];
#pragma unroll
  for (int cg = 0; cg < 4; ++cg)
#pragma unroll
    for (int rr = 0; rr < 4; ++rr) {
      b4[cg][rr]  = bias[cg * 16 + oct * 4 + rr];
      bb1[cg][rr] = b1x1[cg * 16 + oct * 4 + rr];
    }
  bf16x8 a1_0[4], a1_1[4];      // 1x1 weight frags (s=0,1)
#pragma unroll
  for (int cg = 0; cg < 4; ++cg) {
    a1_0[cg] = *(const bf16x8*)(w1b + (cg * 16 + l15) * 64 + 0 * 32 + oct * 8);
    a1_1[cg] = *(const bf16x8*)(w1b + (cg * 16 + l15) * 64 + 1 * 32 + oct * 8);
  }

  {
    const char* gs = (const char*)wsw;
    char* ld = (char*)Ws;
#pragma unroll 1
    for (int i = wv; i < 72; i += 8)
      gload_lds16(gs + i * 1024 + lane * 16, ld + i * 1024);
  }

  const size_t fbase = (size_t)f * PW * PW * CH;
  const char* fbp = (const char*)(inp + fbase);

  {
    const char* tb = fbp + (size_t)h0 * ROWB;
    char* ld = (char*)Xb0;
#pragma unroll 1
    for (int i = wv; i < 43; i += 8) {
      const int ob = i * 1024 + lane * 16;
      const int row = ob / 4352;
      const int rem = ob - row * 4352;
      gload_lds16(tb + (size_t)row * ROWB + rem, ld + i * 1024);
    }
  }

#pragma unroll 1
  for (int it = 0; it < 4; ++it) {
    __syncthreads();                             // stage(it) ready
    u16* Xc = (it & 1) ? Xb1 : Xb0;
    u16* Xn = (it & 1) ? Xb0 : Xb1;
    if (it < 3) {                                // prefetch next tile
      const char* tb = fbp + (size_t)h0 * ROWB + (size_t)(it + 1) * 32 * CH * 2;
      char* ld = (char*)Xn;
#pragma unroll 1
      for (int i = wv; i < 43; i += 8) {
        const int ob = i * 1024 + lane * 16;
        const int row = ob / 4352;
        const int rem = ob - row * 4352;
        gload_lds16(tb + (size_t)row * ROWB + rem, ld + i * 1024);
      }
    }
    const int w0 = it * 32;
    const int pph = h0 + wv + 1;

    // issue xres loads early (T14)
    u16x4 xrv[4][2];
    size_t gaddr[4][2];
#pragma unroll
    for (int cg = 0; cg < 4; ++cg)
#pragma unroll
      for (int pt = 0; pt < 2; ++pt) {
        const int lc = pt * 16 + l15;
        const int ppw = w0 + lc + 1;
        const int unitg = (cg * 2 + (oct >> 1)) ^ (ppw & 7);
        gaddr[cg][pt] = fbase + ((size_t)pph * PW + ppw) * CH + unitg * 8 + (oct & 1) * 4;
        xrv[cg][pt] = *(const u16x4*)(xp + gaddr[cg][pt]);
      }

    f32x4 acc[4][2];
#pragma unroll
    for (int i = 0; i < 4; ++i)
#pragma unroll
      for (int j = 0; j < 2; ++j) acc[i][j] = (f32x4)0.f;

#pragma unroll 1
    for (int s = 0; s < 18; ++s) {
      const int o = s >> 1;
      const int dy = o / 3, dx = o - dy * 3;
      const int half = s & 1;
      bf16x8 a[4];
#pragma unroll
      for (int cg = 0; cg < 4; ++cg) {
        const int gi = (cg * 16 + l15) * 72 + s * 4 + oct;
        a[cg] = *(const bf16x8*)(Ws + ((gi ^ (l15 & 7)) << 3));
      }
#pragma unroll
      for (int pt = 0; pt < 2; ++pt) {
        const int r = wv + dy;
        const int cc = pt * 16 + dx + l15;
        const int p = r * 34 + cc;
        const int co = ((half * 4 + oct) ^ (cc & 7)) << 3;
        bf16x8 b = *(const bf16x8*)((const short*)Xc + p * 64 + co);
#pragma unroll
        for (int cg = 0; cg < 4; ++cg)
          acc[cg][pt] = __builtin_amdgcn_mfma_f32_16x16x32_bf16(a[cg], b, acc[cg][pt], 0, 0, 0);
      }
    }

    __syncthreads();            // all Xc reads done -> reuse as Ys
    u16* Ys = Xc;               // [256 pix][64 ch], XOR swizzle on (p2&7)

    // epilogue 1: x5 = acc + b2 + x(bf16) -> global store + Ys stash
#pragma unroll
    for (int cg = 0; cg < 4; ++cg)
#pragma unroll
      for (int pt = 0; pt < 2; ++pt) {
        const int lc = pt * 16 + l15;
        const int p2 = wv * 32 + lc;
        u16x4 pk;
#pragma unroll
        for (int rr = 0; rr < 4; ++rr) {
          float v = acc[cg][pt][rr] + b4[cg][rr] + bf2f(xrv[cg][pt][rr]);
          pk[rr] = tobf(v);
        }
        *(u16x4*)(outx + gaddr[cg][pt]) = pk;
        const int unit2 = (cg * 2 + (oct >> 1)) ^ (p2 & 7);
        *(u16x4*)(Ys + p2 * 64 + unit2 * 8 + (oct & 1) * 4) = pk;
      }
    __syncthreads();            // Ys visible

    // phase 2: k = wk1 @ x5 + bk1
    f32x4 acc2[4][2];
#pragma unroll
    for (int i = 0; i < 4; ++i)
#pragma unroll
      for (int j = 0; j < 2; ++j) acc2[i][j] = (f32x4)0.f;

#pragma unroll
    for (int pt = 0; pt < 2; ++pt) {
      const int p2 = wv * 32 + pt * 16 + l15;
      const int co0 = ((0 * 4 + oct) ^ (p2 & 7)) << 3;
      const int co1 = ((1 * 4 + oct) ^ (p2 & 7)) << 3;
      bf16x8 bv0 = *(const bf16x8*)((const short*)Ys + p2 * 64 + co0);
      bf16x8 bv1 = *(const bf16x8*)((const short*)Ys + p2 * 64 + co1);
#pragma unroll
      for (int cg = 0; cg < 4; ++cg) {
        acc2[cg][pt] = __builtin_amdgcn_mfma_f32_16x16x32_bf16(a1_0[cg], bv0, acc2[cg][pt], 0, 0, 0);
        acc2[cg][pt] = __builtin_amdgcn_mfma_f32_16x16x32_bf16(a1_1[cg], bv1, acc2[cg][pt], 0, 0, 0);
      }
    }

    // epilogue 2: k + bk1 -> bf16 padded
#pragma unroll
    for (int cg = 0; cg < 4; ++cg)
#pragma unroll
      for (int pt = 0; pt < 2; ++pt) {
        const int lc = pt * 16 + l15;
        const int ppw = w0 + lc + 1;
        const int unit = (cg * 2 + (oct >> 1)) ^ (ppw & 7);
        u16x4 pk;
#pragma unroll
        for (int rr = 0; rr < 4; ++rr)
          pk[rr] = tobf(acc2[cg][pt][rr] + bb1[cg][rr]);
        *(u16x4*)(outk + fbase + ((size_t)pph * PW + ppw) * CH +
                  unit * 8 + (oct & 1) * 4) = pk;
      }
  }
}

// stride-2 3x3 conv 64->9 via bf16 MFMA. Block = (hy, f): 4 out rows x 64
// cols; stage 9 contiguous padded rows whole; A = wk3 [16][576] bf16.
__global__ __launch_bounds__(512) void convs2m_k(
    const u16* __restrict__ inb, const short* __restrict__ w3b,
    const float* __restrict__ bk3, float* __restrict__ sc)
{
  extern __shared__ __align__(16) char smem[];
  u16* St = (u16*)smem;                 // 9 rows x 130 px x 64 ch = 149760 B
  const int hy = blockIdx.x;            // 0..15 -> out rows 4hy..4hy+3
  const int f  = blockIdx.y;            // 0..15
  const int tid = threadIdx.x;
  const int lane = tid & 63;
  const int wv = __builtin_amdgcn_readfirstlane(tid >> 6);  // 0..7
  const int l15 = lane & 15;
  const int oct = lane >> 4;

  const char* fbp = (const char*)(inb + (size_t)f * PW * PW * CH) +
                    (size_t)(8 * hy) * ROWB;
  char* ld = (char*)St;
#pragma unroll 1
  for (int g = tid; g < 9360; g += 512)         // 9360 x 16B granules
    gload_lds16(fbp + g * 16, ld + g * 16);
  __syncthreads();

  f32x4 acc[2];
  acc[0] = (f32x4)0.f;
  acc[1] = (f32x4)0.f;

#pragma unroll 2
  for (int s = 0; s < 18; ++s) {
    const int o = s >> 1;                       // tap 0..8
    const int dy = o / 3, dx = o - dy * 3;
    const int half = s & 1;                     // cin half
    bf16x8 a = *(const bf16x8*)(w3b + l15 * 576 + s * 32 + oct * 8);
#pragma unroll
    for (int pg = 0; pg < 2; ++pg) {
      const int g = wv * 2 + pg;                // px-group 0..15
      const int ho_l = g >> 2, wg = g & 3;
      const int wo = wg * 16 + l15;
      const int irow = 2 * ho_l + dy;           // 0..8
      const int ipx = 2 * wo + dx;              // 0..128 (== global ppw)
      const int slot = (half * 4 + oct) ^ (ipx & 7);
      bf16x8 b = *(const bf16x8*)((const short*)St + (irow * PW + ipx) * 64 + slot * 8);
      acc[pg] = __builtin_amdgcn_mfma_f32_16x16x32_bf16(a, b, acc[pg], 0, 0, 0);
    }
  }

#pragma unroll
  for (int pg = 0; pg < 2; ++pg) {
    const int g = wv * 2 + pg;
    const int ho = hy * 4 + (g >> 2);
    const int wo = (g & 3) * 16 + l15;
#pragma unroll
    for (int rr = 0; rr < 4; ++rr) {
      const int kk = oct * 4 + rr;
      if (kk < 9)
        sc[((size_t)f * 9 + kk) * 4096 + ho * 64 + wo] = acc[pg][rr] + bk3[kk];
    }
  }
}

// Fused softmax + weighted patch reduce from padded swizzled bf16 x5.
// R17: 512 threads, t-loop split across wave-halves (waves 0-3: t 0..3,
// waves 4-7: t 4..7) -> per-thread load chain 72 -> 36, waves/CU 4 -> 8.
// th=1 partials via LDS, th=0 reduces and stores.
__global__ __launch_bounds__(512) void gather2_k(
    const u16* __restrict__ x5p, const float* __restrict__ sc,
    float* __restrict__ out)
{
  const int hx = blockIdx.x;       // wo half (0..1)
  const int ho = blockIdx.y;       // 0..63
  const int b  = blockIdx.z;       // 0..1
  const int wo0 = hx * 32;
  __shared__ float wl[32 * 73];    // 9344 B
  __shared__ float Ps[32 * 64];    // 8192 B  [wol][u*8+j]
  const int tid = threadIdx.x;
  for (int e = tid; e < 32 * 72; e += 512) {
    const int wo = e & 31, k = e >> 5;
    const int t = k / 9, kk = k - t * 9;
    wl[wo * 73 + k] = sc[((size_t)((b * 8 + t) * 9 + kk)) * 4096 + ho * 64 + wo0 + wo];
  }
  __syncthreads();
  if (tid < 32) {
    float* row = &wl[tid * 73];
    float mx = -1e30f;
#pragma unroll
    for (int i = 0; i < 72; ++i) mx = fmaxf(mx, row[i]);
    float sum = 0.f;
#pragma unroll
    for (int i = 0; i < 72; ++i) { float e2 = __expf(row[i] - mx); row[i] = e2; sum += e2; }
    const float inv = 1.f / sum;
#pragma unroll
    for (int i = 0; i < 72; ++i) row[i] *= inv;
  }
  __syncthreads();
  const int lane = tid & 63;
  const int wv = tid >> 6;                 // 0..7
  const int u = lane & 7;                  // channel octet
  const int wol = (lane >> 3) + (wv & 3) * 8;   // 0..31
  const int th = wv >> 2;                  // t-half 0..1
  const int wo = wo0 + wol;
  float acc[8];
#pragma unroll
  for (int j = 0; j < 8; ++j) acc[j] = 0.f;
#pragma unroll 1
  for (int tt = 0; tt < 4; ++tt) {
    const int t = th * 4 + tt;
    const int f = b * 8 + t;
    const size_t fb = (size_t)f * PW * PW * CH;
    const float* wrow = &wl[wol * 73 + t * 9];
#pragma unroll
    for (int di = 0; di < 3; ++di) {
      const int pph = min(max(2 * ho + di, 1), 128);
#pragma unroll
      for (int dj = 0; dj < 3; ++dj) {
        const int ppw = min(max(2 * wo + dj, 1), 128);
        const int unit = u ^ (ppw & 7);
        u16x8 pk = *(const u16x8*)(x5p + fb + ((size_t)pph * PW + ppw) * CH + unit * 8);
        const float wq = wrow[di * 3 + dj];
#pragma unroll
        for (int j = 0; j < 8; ++j)
          acc[j] = fmaf(bf2f(pk[j]), wq, acc[j]);
      }
    }
  }
  if (th == 1) {
#pragma unroll
    for (int j = 0; j < 8; ++j) Ps[wol * 64 + u * 8 + j] = acc[j];
  }
  __syncthreads();
  if (th == 0) {
    const int obase = ((b * 64 + u * 8) * 64 + ho) * 64 + wo;
#pragma unroll
    for (int j = 0; j < 8; ++j)
      out[obase + j * 4096] = acc[j] + Ps[wol * 64 + u * 8 + j];
  }
}

extern "C" void kernel_launch(void* const* d_in, const int* in_sizes, int n_in,
                              void* d_out, int out_size, void* d_ws, size_t ws_size,
                              hipStream_t stream)
{
  const float* x   = (const float*)d_in[0];
  const float* w1  = (const float*)d_in[1];
  const float* b1  = (const float*)d_in[2];
  const float* w2  = (const float*)d_in[3];
  const float* b2  = (const float*)d_in[4];
  const float* wk1 = (const float*)d_in[5];
  const float* bk1 = (const float*)d_in[6];
  const float* wk2 = (const float*)d_in[7];
  const float* bk2 = (const float*)d_in[8];
  const float* wk3 = (const float*)d_in[9];
  const float* bk3 = (const float*)d_in[10];
  float* outp = (float*)d_out;

  const size_t PADB = (size_t)16 * PW * PW * CH * 2;   // 34,611,200 B
  char* ws = (char*)d_ws;
  u16*  P1      = (u16*)ws;                            // x bf16, then kf2
  u16*  P2      = (u16*)(ws + PADB);                   // res1
  u16*  P3      = (u16*)(ws + 2 * PADB);               // k
  u16*  P4      = (u16*)(ws + 3 * PADB);               // x5 bf16
  u16*  P5      = (u16*)(ws + 4 * PADB);               // sm
  float* scores = (float*)(ws + 5 * PADB);             // 2.25 MB
  short* Wp1    = (short*)(ws + 5 * PADB + 2359296);
  short* Wp2    = Wp1 + 36864;
  short* Wp4    = Wp2 + 36864;
  short* Wk1b   = Wp4 + 36864;                         // 4096 bf16
  short* Wp3    = Wk1b + 4096;                         // 9216 bf16 (wk3, padded)
  (void)ws_size; (void)in_sizes; (void)n_in; (void)out_size;

  hipFuncSetAttribute((const void*)conv3x3_pers_k,
                      hipFuncAttributeMaxDynamicSharedMemorySize, 161792);
  hipFuncSetAttribute((const void*)convx5_pers_k,
                      hipFuncAttributeMaxDynamicSharedMemorySize, 161792);
  hipFuncSetAttribute((const void*)convs2m_k,
                      hipFuncAttributeMaxDynamicSharedMemorySize, 149760);

  // weight packs (merged)
  prep_k<<<dim3(180, 3), 256, 0, stream>>>(w1, w2, wk2, wk1, wk3,
                                           Wp1, Wp2, Wp4, Wk1b, Wp3);
  // x -> padded swizzled bf16 (ring = 0), coalesced transpose version
  xprep_k<<<dim3(16, PW), 256, 0, stream>>>(x, P1);
  // zero pad rings for res1, k
  padzero_k<<<dim3(17, 16, 2), 256, 0, stream>>>(P2, P3);

  // 1: res1 = lrelu(conv(x, w1) + b1)                    -> P2
  conv3x3_pers_k<<<dim3(256), 512, 161792, stream>>>(P1, Wp1, b1, P2);
  // 2: sm = res1 * shift(res1)                           -> P5 (ring 0)
  shmul_k<<<dim3(16, PW), 256, 0, stream>>>(P2, P5);
  // 3: x5 = x + conv(sm, w2) + b2 (bf16) -> P4; k = wk1@x5 + bk1 -> P3
  convx5_pers_k<<<dim3(256), 512, 161792, stream>>>(P5, Wp2, b2, P1, Wk1b, bk1, P4, P3);
  // 4: kf2 = lrelu(conv(k, wk2) + bk2)                   -> P1 (ring 0 from xprep)
  conv3x3_pers_k<<<dim3(256), 512, 161792, stream>>>(P3, Wp4, bk2, P1);
  // 5: scores = conv_s2(kf2, wk3) + bk3 via MFMA         -> scores
  convs2m_k<<<dim3(16, 16), 512, 149760, stream>>>(P1, Wp3, bk3, scores);
  // 6: fused softmax + weighted gather (split-t, 8 waves)
  gather2_k<<<dim3(2, 64, 2), 512, 0, stream>>>(P4, scores, outp);
}